// Round 2
// baseline (835.432 us; speedup 1.0000x reference)
//
#include <hip/hip_runtime.h>
#include <hip/hip_bf16.h>

#define B 64
#define T_ENC 4096
#define H_ENC 512
#define H_DEC 512
#define ATTN 256

#define BM 128           // rows per chunk/block
#define BK 64            // k-step
#define LDA_A 72         // Abuf row stride in shorts (144 B, 16B-aligned, ~2-way banks)
#define NCH_PER_B (T_ENC / BM)     // 32 chunks per batch
#define NCHUNKS ((B * T_ENC) / BM) // 2048

typedef __attribute__((ext_vector_type(8))) short bf16x8;
typedef __attribute__((ext_vector_type(4))) float f32x4;

__device__ __forceinline__ ushort2 cvt2_bf16(float x, float y) {
    __hip_bfloat162 h = __float22bfloat162_rn(make_float2(x, y));
    return *reinterpret_cast<ushort2*>(&h);
}

__device__ __forceinline__ float fast_tanh(float x) {
    float ax = fabsf(x);
    float e = __expf(2.0f * fminf(ax, 15.0f));
    float t = 1.0f - 2.0f / (e + 1.0f);
    return copysignf(t, x);
}

// ---------------------------------------------------------------------------
// Kernel 0: one-time W_enc fp32 -> bf16, plain row-major (256 KB, L2-resident)
// ---------------------------------------------------------------------------
__global__ void convw_kernel(const float* __restrict__ W,
                             unsigned short* __restrict__ out) {
    int g = blockIdx.x * 256 + threadIdx.x;  // 16384 chunks of 8 elems
    const float* src = W + (size_t)g * 8;
    float4 x0 = *(const float4*)(src);
    float4 x1 = *(const float4*)(src + 4);
    ushort2 a0 = cvt2_bf16(x0.x, x0.y);
    ushort2 a1 = cvt2_bf16(x0.z, x0.w);
    ushort2 a2 = cvt2_bf16(x1.x, x1.y);
    ushort2 a3 = cvt2_bf16(x1.z, x1.w);
    ushort4 lo = {a0.x, a0.y, a1.x, a1.y};
    ushort4 hi = {a2.x, a2.y, a3.x, a3.y};
    *(ushort4*)(out + (size_t)g * 8)     = lo;
    *(ushort4*)(out + (size_t)g * 8 + 4) = hi;
}

// ---------------------------------------------------------------------------
// Kernel 1: dec_proj[b,a] = dot(decoder_state[b,:], W_dec[a,:])
// ---------------------------------------------------------------------------
__global__ void decproj_kernel(const float* __restrict__ dec,
                               const float* __restrict__ Wdec,
                               float* __restrict__ dproj) {
    __shared__ float sdec[H_DEC];
    int b = blockIdx.x;
    int tid = threadIdx.x;
    sdec[tid]       = dec[b * H_DEC + tid];
    sdec[tid + 256] = dec[b * H_DEC + tid + 256];
    __syncthreads();
    const float* wrow = Wdec + (size_t)tid * H_DEC;
    float acc = 0.0f;
#pragma unroll 4
    for (int k = 0; k < H_DEC; k += 4) {
        float4 w4 = *(const float4*)(wrow + k);
        acc += w4.x * sdec[k] + w4.y * sdec[k + 1] + w4.z * sdec[k + 2] + w4.w * sdec[k + 3];
    }
    dproj[b * ATTN + tid] = acc;
}

// ---------------------------------------------------------------------------
// Kernel 2 (FUSED): per 128-row chunk:
//   GEMM (BM=128, BK=64, 4 waves, wave tile 64x128)
//   - A: enc fp32 -> bf16, reg-prefetched (T14) + double-buffered LDS,
//        ONE barrier per K-step.
//   - B: W_enc bf16 fragments read DIRECTLY from global (L2-resident, no LDS).
//   -> scores -> chunk-local softmax numerators -> partial context.
// ---------------------------------------------------------------------------
__global__ __launch_bounds__(256, 2) void fused_kernel(
    const float* __restrict__ enc,             // (B*T, 512) fp32
    const unsigned short* __restrict__ wencb,  // (256, 512) bf16 row-major
    const float* __restrict__ dproj,           // (B, 256)
    const float* __restrict__ v,               // (256)
    float* __restrict__ scores,                // (B*T)
    float* __restrict__ ctxp,                  // (NCHUNKS, 512)
    float* __restrict__ ml)                    // (NCHUNKS, 2)
{
    __shared__ __align__(16) unsigned short Abuf[2][BM * LDA_A];  // 2 x 18 KB
    __shared__ float sPart[BM * 2];
    __shared__ float sP[BM];
    __shared__ float sW[4];

    const int tid  = threadIdx.x;
    const int wave = tid >> 6;
    const int lane = tid & 63;
    const int quad = lane >> 4;
    const int l16  = lane & 15;
    const int wr   = wave >> 1;       // row half (0..1): rows wr*64..+63
    const int wc   = wave & 1;        // col half (0..1): cols wc*128..+127
    const int chunk = blockIdx.x;
    const int m0   = chunk * BM;
    const int b    = chunk >> 5;      // chunk / NCH_PER_B

    f32x4 acc[4][8];
#pragma unroll
    for (int mi = 0; mi < 4; ++mi)
#pragma unroll
        for (int ni = 0; ni < 8; ++ni) {
            f32x4 z = {0.0f, 0.0f, 0.0f, 0.0f};
            acc[mi][ni] = z;
        }

    // Per-thread A staging geometry: 4 reps x (2 float4) covering 128x64 fp32.
    const int sidx = tid * 8;                 // rep 0 element index
    // rep rp: idx = rp*2048 + tid*8 ; r = idx>>6 ; c = idx&63
    float4 pA[8];

    // ---- prologue: prefetch A(k=0) ----
#pragma unroll
    for (int rp = 0; rp < 4; ++rp) {
        int idx = rp * 2048 + sidx;
        int r = idx >> 6, c = idx & 63;
        const float* p = enc + (size_t)(m0 + r) * H_ENC + c;
        pA[rp * 2]     = *(const float4*)(p);
        pA[rp * 2 + 1] = *(const float4*)(p + 4);
    }

    for (int k0 = 0; k0 < H_ENC; k0 += BK) {
        const int cur = (k0 >> 6) & 1;
        // ---- cvt prefetched A -> bf16, write Abuf[cur] ----
#pragma unroll
        for (int rp = 0; rp < 4; ++rp) {
            int idx = rp * 2048 + sidx;
            int r = idx >> 6, c = idx & 63;
            float4 x0 = pA[rp * 2];
            float4 x1 = pA[rp * 2 + 1];
            ushort2 a0 = cvt2_bf16(x0.x, x0.y);
            ushort2 a1 = cvt2_bf16(x0.z, x0.w);
            ushort2 a2 = cvt2_bf16(x1.x, x1.y);
            ushort2 a3 = cvt2_bf16(x1.z, x1.w);
            union { bf16x8 v8; unsigned short u[8]; } U;
            U.u[0] = a0.x; U.u[1] = a0.y; U.u[2] = a1.x; U.u[3] = a1.y;
            U.u[4] = a2.x; U.u[5] = a2.y; U.u[6] = a3.x; U.u[7] = a3.y;
            *(bf16x8*)(&Abuf[cur][r * LDA_A + c]) = U.v8;
        }
        __syncthreads();   // writers of Abuf[cur] visible; prev compute done

        // ---- issue A(k+1) prefetch: flies during MFMA + B reads ----
        if (k0 + BK < H_ENC) {
#pragma unroll
            for (int rp = 0; rp < 4; ++rp) {
                int idx = rp * 2048 + sidx;
                int r = idx >> 6, c = idx & 63;
                const float* p = enc + (size_t)(m0 + r) * H_ENC + (k0 + BK) + c;
                pA[rp * 2]     = *(const float4*)(p);
                pA[rp * 2 + 1] = *(const float4*)(p + 4);
            }
        }

        // ---- compute: A from LDS, B direct from L2-resident global ----
#pragma unroll
        for (int kk = 0; kk < 2; ++kk) {
            const int ca = kk * 32 + quad * 8;   // k offset within K-step
            bf16x8 af[4], bfv[8];
#pragma unroll
            for (int mi = 0; mi < 4; ++mi)
                af[mi] = *(const bf16x8*)(&Abuf[cur][(wr * 64 + mi * 16 + l16) * LDA_A + ca]);
#pragma unroll
            for (int ni = 0; ni < 8; ++ni) {
                int a = wc * 128 + ni * 16 + l16;
                bfv[ni] = *(const bf16x8*)(wencb + (size_t)a * H_ENC + k0 + ca);
            }
#pragma unroll
            for (int mi = 0; mi < 4; ++mi)
#pragma unroll
                for (int ni = 0; ni < 8; ++ni)
                    acc[mi][ni] = __builtin_amdgcn_mfma_f32_16x16x32_bf16(
                        af[mi], bfv[ni], acc[mi][ni], 0, 0, 0);
        }
        __syncthreads();   // compute done before Abuf[cur^1... ] rewrite next iter
    }

    // ---- epilogue: tanh(c + dec_proj) * v, reduce over a ----
    float decp[8], vv[8];
#pragma unroll
    for (int ni = 0; ni < 8; ++ni) {
        int a = wc * 128 + ni * 16 + l16;
        decp[ni] = dproj[b * ATTN + a];
        vv[ni]   = v[a];
    }
#pragma unroll
    for (int mi = 0; mi < 4; ++mi) {
#pragma unroll
        for (int r = 0; r < 4; ++r) {
            float sum = 0.0f;
#pragma unroll
            for (int ni = 0; ni < 8; ++ni)
                sum += fast_tanh(acc[mi][ni][r] + decp[ni]) * vv[ni];
            sum += __shfl_xor(sum, 1);
            sum += __shfl_xor(sum, 2);
            sum += __shfl_xor(sum, 4);
            sum += __shfl_xor(sum, 8);
            if (l16 == 0)
                sPart[(wr * 64 + mi * 16 + quad * 4 + r) * 2 + wc] = sum;
        }
    }
    __syncthreads();

    // ---- chunk-local softmax numerators (128 rows = waves 0,1) ----
    const bool act = tid < BM;
    float s = -INFINITY;
    if (act) {
        s = sPart[tid * 2] + sPart[tid * 2 + 1];
        scores[m0 + tid] = s;
    }
    float m = s;
#pragma unroll
    for (int o = 1; o < 64; o <<= 1) m = fmaxf(m, __shfl_xor(m, o));
    if (act && lane == 0) sW[wave] = m;
    __syncthreads();
    const float M = fmaxf(sW[0], sW[1]);
    float p = act ? __expf(s - M) : 0.0f;
    float l = p;
#pragma unroll
    for (int o = 1; o < 64; o <<= 1) l += __shfl_xor(l, o);
    if (act && lane == 0) sW[2 + wave] = l;
    if (act) sP[tid] = p;
    __syncthreads();
    if (tid == 0) {
        ml[chunk * 2]     = M;
        ml[chunk * 2 + 1] = sW[2] + sW[3];
    }

    // ---- pass 2: partial context from cache-hot enc chunk (fp32) ----
    int e0 = tid * 2;
    const float* ebase = enc + (size_t)m0 * H_ENC + e0;
    float cx = 0.0f, cy = 0.0f;
#pragma unroll 8
    for (int tt = 0; tt < BM; ++tt) {
        float wt = sP[tt];
        float2 x = *(const float2*)(ebase + (size_t)tt * H_ENC);
        cx += wt * x.x;
        cy += wt * x.y;
    }
    float* cp = ctxp + (size_t)chunk * H_ENC + e0;
    cp[0] = cx;
    cp[1] = cy;
}

// ---------------------------------------------------------------------------
// Kernel 3: combine — global softmax over 32 chunks, write attn + context
// ---------------------------------------------------------------------------
__global__ __launch_bounds__(256) void combine_kernel(
    const float* __restrict__ scores,  // (B*T)
    const float* __restrict__ ctxp,    // (NCHUNKS, 512)
    const float* __restrict__ ml,      // (NCHUNKS, 2)
    float* __restrict__ out)           // ctx (B,512) then attn (B,4096)
{
    __shared__ float sc[NCH_PER_B];
    __shared__ float sML[2];
    const int b = blockIdx.x;
    const int tid = threadIdx.x;
    const int nch = NCH_PER_B;  // 32

    float m_in = -INFINITY, l_in = 0.0f;
    if (tid < nch) {
        m_in = ml[(b * nch + tid) * 2];
        l_in = ml[(b * nch + tid) * 2 + 1];
    }
    if (tid < 64) {
        float M = m_in;
#pragma unroll
        for (int o = 1; o < 32; o <<= 1) M = fmaxf(M, __shfl_xor(M, o));
        float scale = (tid < nch) ? __expf(m_in - M) : 0.0f;
        float L = l_in * scale;
#pragma unroll
        for (int o = 1; o < 32; o <<= 1) L += __shfl_xor(L, o);
        if (tid < nch) sc[tid] = scale;
        if (tid == 0) { sML[0] = M; sML[1] = L; }
    }
    __syncthreads();
    const float M = sML[0];
    const float invL = 1.0f / sML[1];

    // attn weights: exact softmax from raw scores
    const float* sb = scores + (size_t)b * T_ENC;
    float* attn = out + B * H_ENC + (size_t)b * T_ENC;
#pragma unroll
    for (int i = 0; i < 16; ++i) {
        int t = i * 256 + tid;
        attn[t] = __expf(sb[t] - M) * invL;
    }

    // context: merge chunk partials
    int e0 = tid * 2;
    const float* cp = ctxp + ((size_t)b * nch) * H_ENC + e0;
    float cx = 0.0f, cy = 0.0f;
#pragma unroll 4
    for (int i = 0; i < nch; ++i) {
        float s2 = sc[i];
        float2 x = *(const float2*)(cp + (size_t)i * H_ENC);
        cx += s2 * x.x;
        cy += s2 * x.y;
    }
    out[b * H_ENC + e0]     = cx * invL;
    out[b * H_ENC + e0 + 1] = cy * invL;
}

extern "C" void kernel_launch(void* const* d_in, const int* in_sizes, int n_in,
                              void* d_out, int out_size, void* d_ws, size_t ws_size,
                              hipStream_t stream) {
    const float* dec  = (const float*)d_in[0];
    const float* enc  = (const float*)d_in[1];
    const float* Wenc = (const float*)d_in[2];
    const float* Wdec = (const float*)d_in[3];
    const float* v    = (const float*)d_in[4];
    float* out = (float*)d_out;
    float* ws  = (float*)d_ws;

    float* scores = ws;                                   // 262144 floats
    float* dproj  = scores + (size_t)B * T_ENC;           // 16384 floats
    unsigned short* wencb = (unsigned short*)(dproj + B * ATTN);  // 131072 shorts
    float* ctxp = dproj + B * ATTN + (ATTN * H_ENC) / 2;  // NCHUNKS*512 floats
    float* ml   = ctxp + (size_t)NCHUNKS * H_ENC;         // NCHUNKS*2 floats

    hipLaunchKernelGGL(convw_kernel, dim3((ATTN * H_ENC) / (256 * 8)), dim3(256), 0, stream,
                       Wenc, wencb);
    hipLaunchKernelGGL(decproj_kernel, dim3(B), dim3(256), 0, stream, dec, Wdec, dproj);
    hipLaunchKernelGGL(fused_kernel, dim3(NCHUNKS), dim3(256), 0, stream,
                       enc, wencb, dproj, v, scores, ctxp, ml);
    hipLaunchKernelGGL(combine_kernel, dim3(B), dim3(256), 0, stream,
                       scores, ctxp, ml, out);
}

// Round 3
// 787.252 us; speedup vs baseline: 1.0612x; 1.0612x over previous
//
#include <hip/hip_runtime.h>
#include <hip/hip_bf16.h>

#define B 64
#define T_ENC 4096
#define H_ENC 512
#define H_DEC 512
#define ATTN 256

#define BM 128           // rows per chunk/block
#define BK 64            // k-step
#define LDA_A 72         // Abuf row stride in shorts (144 B, 16B-aligned, ~2-way banks)
#define NCH_PER_B (T_ENC / BM)     // 32 chunks per batch
#define NCHUNKS ((B * T_ENC) / BM) // 2048

typedef __attribute__((ext_vector_type(8))) short bf16x8;
typedef __attribute__((ext_vector_type(4))) float f32x4;

__device__ __forceinline__ ushort2 cvt2_bf16(float x, float y) {
    __hip_bfloat162 h = __float22bfloat162_rn(make_float2(x, y));
    return *reinterpret_cast<ushort2*>(&h);
}

__device__ __forceinline__ float fast_tanh(float x) {
    float ax = fabsf(x);
    float e = __expf(2.0f * fminf(ax, 15.0f));
    float t = 1.0f - 2.0f / (e + 1.0f);
    return copysignf(t, x);
}

__device__ __forceinline__ void gload_lds16(const void* g, void* l) {
    __builtin_amdgcn_global_load_lds(
        (const __attribute__((address_space(1))) void*)g,
        (__attribute__((address_space(3))) void*)l, 16, 0, 0);
}

// ---------------------------------------------------------------------------
// Kernel 0: W_enc fp32 -> bf16, PRE-SWIZZLED tile layout for global_load_lds.
// Layout: 8 k-tiles of [256 rows][128 B]; within a row-tile, byte col bc
// stores W[r][ t*64 + ((bc ^ ((r&7)<<4)) >> 1) ].  The GEMM stages each
// 32 KB tile LINEARLY into LDS (global_load_lds requirement) and applies
// the same XOR on ds_read -> conflict-free b128 fragment reads.
// ---------------------------------------------------------------------------
__global__ void convw_kernel(const float* __restrict__ W,
                             unsigned short* __restrict__ out) {
    int g = blockIdx.x * 256 + threadIdx.x;  // 16384 chunks of 16 B
    int j = g & 7;                            // 16-B chunk within row-tile
    int r = (g >> 3) & 255;                   // attn row
    int t = g >> 11;                          // k-tile
    int c0 = t * 64 + ((j ^ (r & 7)) << 3);   // source k (8 consecutive)
    const float* src = W + (size_t)r * H_ENC + c0;
    float4 x0 = *(const float4*)(src);
    float4 x1 = *(const float4*)(src + 4);
    ushort2 a0 = cvt2_bf16(x0.x, x0.y);
    ushort2 a1 = cvt2_bf16(x0.z, x0.w);
    ushort2 a2 = cvt2_bf16(x1.x, x1.y);
    ushort2 a3 = cvt2_bf16(x1.z, x1.w);
    ushort4 lo = {a0.x, a0.y, a1.x, a1.y};
    ushort4 hi = {a2.x, a2.y, a3.x, a3.y};
    *(ushort4*)(out + (size_t)g * 8)     = lo;
    *(ushort4*)(out + (size_t)g * 8 + 4) = hi;
}

// ---------------------------------------------------------------------------
// Kernel 1: dec_proj[b,a] = dot(decoder_state[b,:], W_dec[a,:])
// ---------------------------------------------------------------------------
__global__ void decproj_kernel(const float* __restrict__ dec,
                               const float* __restrict__ Wdec,
                               float* __restrict__ dproj) {
    __shared__ float sdec[H_DEC];
    int b = blockIdx.x;
    int tid = threadIdx.x;
    sdec[tid]       = dec[b * H_DEC + tid];
    sdec[tid + 256] = dec[b * H_DEC + tid + 256];
    __syncthreads();
    const float* wrow = Wdec + (size_t)tid * H_DEC;
    float acc = 0.0f;
#pragma unroll 4
    for (int k = 0; k < H_DEC; k += 4) {
        float4 w4 = *(const float4*)(wrow + k);
        acc += w4.x * sdec[k] + w4.y * sdec[k + 1] + w4.z * sdec[k + 2] + w4.w * sdec[k + 3];
    }
    dproj[b * ATTN + tid] = acc;
}

// ---------------------------------------------------------------------------
// Kernel 2 (FUSED): per 128-row chunk:
//   GEMM (BM=128, BK=64, 4 waves, wave tile 64x128)
//   - B: W_enc bf16 via global_load_lds (pre-swizzled, coalesced, async)
//   - A: enc fp32 reg-prefetched one K-step ahead (T14); the prefetch
//        survives the end-of-compute barrier because that barrier is a RAW
//        s_barrier (no vmcnt drain). The mid-step __syncthreads drain is
//        exactly the wait needed for B's gload_lds + cvt ds_writes.
//   -> scores -> chunk-local softmax numerators -> partial context.
// ---------------------------------------------------------------------------
__global__ __launch_bounds__(256, 2) void fused_kernel(
    const float* __restrict__ enc,             // (B*T, 512) fp32
    const unsigned short* __restrict__ wencb,  // swizzled (8,256,64) bf16
    const float* __restrict__ dproj,           // (B, 256)
    const float* __restrict__ v,               // (256)
    float* __restrict__ scores,                // (B*T)
    float* __restrict__ ctxp,                  // (NCHUNKS, 512)
    float* __restrict__ ml)                    // (NCHUNKS, 2)
{
    __shared__ __align__(16) unsigned short Abuf[BM * LDA_A];  // 18 KB
    __shared__ __align__(16) unsigned short Bbuf[ATTN * BK];   // 32 KB linear
    __shared__ float sPart[BM * 2];
    __shared__ float sP[BM];
    __shared__ float sW[4];

    const int tid  = threadIdx.x;
    const int wave = tid >> 6;
    const int lane = tid & 63;
    const int quad = lane >> 4;
    const int l16  = lane & 15;
    const int wr   = wave >> 1;       // row half (0..1): rows wr*64..+63
    const int wc   = wave & 1;        // col half (0..1): cols wc*128..+127
    const int swz  = (l16 & 7) << 4;  // B read-side XOR (matches convw)
    const int chunk = blockIdx.x;
    const int m0   = chunk * BM;
    const int b    = chunk >> 5;      // chunk / NCH_PER_B

    f32x4 acc[4][8];
#pragma unroll
    for (int mi = 0; mi < 4; ++mi)
#pragma unroll
        for (int ni = 0; ni < 8; ++ni) {
            f32x4 z = {0.0f, 0.0f, 0.0f, 0.0f};
            acc[mi][ni] = z;
        }

    const char* wb = (const char*)wencb;
    char* bb = (char*)Bbuf;

    // Per-thread A staging geometry: 4 reps x (2 float4) covering 128x64 fp32.
    const int sidx = tid * 8;  // rep rp: idx = rp*2048 + sidx; r = idx>>6; c = idx&63
    float4 pA[8];

    // ---- prologue: prefetch A(k=0) into registers ----
#pragma unroll
    for (int rp = 0; rp < 4; ++rp) {
        int idx = rp * 2048 + sidx;
        int r = idx >> 6, c = idx & 63;
        const float* p = enc + (size_t)(m0 + r) * H_ENC + c;
        pA[rp * 2]     = *(const float4*)(p);
        pA[rp * 2 + 1] = *(const float4*)(p + 4);
    }

    for (int k0 = 0; k0 < H_ENC; k0 += BK) {
        const int t = k0 >> 6;
        // ---- stage B: async 32 KB linear copy (bf16, L2-resident) ----
#pragma unroll
        for (int i = 0; i < 8; ++i) {
            int u = i * 256 + tid;  // 16-B unit: wave-uniform base + lane*16
            gload_lds16(wb + (((size_t)t * 2048 + u) << 4), bb + (u << 4));
        }
        // ---- cvt prefetched A -> bf16, write Abuf (b128 LDS writes) ----
#pragma unroll
        for (int rp = 0; rp < 4; ++rp) {
            int idx = rp * 2048 + sidx;
            int r = idx >> 6, c = idx & 63;
            float4 x0 = pA[rp * 2];
            float4 x1 = pA[rp * 2 + 1];
            ushort2 a0 = cvt2_bf16(x0.x, x0.y);
            ushort2 a1 = cvt2_bf16(x0.z, x0.w);
            ushort2 a2 = cvt2_bf16(x1.x, x1.y);
            ushort2 a3 = cvt2_bf16(x1.z, x1.w);
            union { bf16x8 v8; unsigned short u[8]; } U;
            U.u[0] = a0.x; U.u[1] = a0.y; U.u[2] = a1.x; U.u[3] = a1.y;
            U.u[4] = a2.x; U.u[5] = a2.y; U.u[6] = a3.x; U.u[7] = a3.y;
            *(bf16x8*)(&Abuf[r * LDA_A + c]) = U.v8;
        }
        __syncthreads();  // drains vmcnt(0)+lgkmcnt(0): B(k) landed, A writes visible

        // ---- issue A(k+1) prefetch: flies through compute AND the raw
        //      end-of-step barrier (no drain there) ----
        if (k0 + BK < H_ENC) {
#pragma unroll
            for (int rp = 0; rp < 4; ++rp) {
                int idx = rp * 2048 + sidx;
                int r = idx >> 6, c = idx & 63;
                const float* p = enc + (size_t)(m0 + r) * H_ENC + (k0 + BK) + c;
                pA[rp * 2]     = *(const float4*)(p);
                pA[rp * 2 + 1] = *(const float4*)(p + 4);
            }
        }

        // ---- compute: 2 x (12 ds_read_b128 + 32 MFMA) ----
#pragma unroll
        for (int kk = 0; kk < 2; ++kk) {
            bf16x8 af[4], bfv[8];
            const int ca = kk * 32 + quad * 8;   // A bf16 col
            const int dc = kk * 64 + quad * 16;  // B byte col (pre-swizzle)
#pragma unroll
            for (int mi = 0; mi < 4; ++mi)
                af[mi] = *(const bf16x8*)(&Abuf[(wr * 64 + mi * 16 + l16) * LDA_A + ca]);
#pragma unroll
            for (int ni = 0; ni < 8; ++ni) {
                int a = wc * 128 + ni * 16 + l16;
                bfv[ni] = *(const bf16x8*)(bb + a * 128 + (dc ^ swz));
            }
#pragma unroll
            for (int mi = 0; mi < 4; ++mi)
#pragma unroll
                for (int ni = 0; ni < 8; ++ni)
                    acc[mi][ni] = __builtin_amdgcn_mfma_f32_16x16x32_bf16(
                        af[mi], bfv[ni], acc[mi][ni], 0, 0, 0);
        }
        // Raw barrier: execution sync only (protects Abuf/Bbuf overwrite next
        // iter). Own ds_reads already complete (counted lgkmcnt before MFMA);
        // deliberately does NOT drain the A(k+1) prefetch.
        __builtin_amdgcn_s_barrier();
    }

    // ---- epilogue: tanh(c + dec_proj) * v, reduce over a ----
    float decp[8], vv[8];
#pragma unroll
    for (int ni = 0; ni < 8; ++ni) {
        int a = wc * 128 + ni * 16 + l16;
        decp[ni] = dproj[b * ATTN + a];
        vv[ni]   = v[a];
    }
#pragma unroll
    for (int mi = 0; mi < 4; ++mi) {
#pragma unroll
        for (int r = 0; r < 4; ++r) {
            float sum = 0.0f;
#pragma unroll
            for (int ni = 0; ni < 8; ++ni)
                sum += fast_tanh(acc[mi][ni][r] + decp[ni]) * vv[ni];
            sum += __shfl_xor(sum, 1);
            sum += __shfl_xor(sum, 2);
            sum += __shfl_xor(sum, 4);
            sum += __shfl_xor(sum, 8);
            if (l16 == 0)
                sPart[(wr * 64 + mi * 16 + quad * 4 + r) * 2 + wc] = sum;
        }
    }
    __syncthreads();

    // ---- chunk-local softmax numerators (128 rows = waves 0,1) ----
    const bool act = tid < BM;
    float s = -INFINITY;
    if (act) {
        s = sPart[tid * 2] + sPart[tid * 2 + 1];
        scores[m0 + tid] = s;
    }
    float m = s;
#pragma unroll
    for (int o = 1; o < 64; o <<= 1) m = fmaxf(m, __shfl_xor(m, o));
    if (act && lane == 0) sW[wave] = m;
    __syncthreads();
    const float M = fmaxf(sW[0], sW[1]);
    float p = act ? __expf(s - M) : 0.0f;
    float l = p;
#pragma unroll
    for (int o = 1; o < 64; o <<= 1) l += __shfl_xor(l, o);
    if (act && lane == 0) sW[2 + wave] = l;
    if (act) sP[tid] = p;
    __syncthreads();
    if (tid == 0) {
        ml[chunk * 2]     = M;
        ml[chunk * 2 + 1] = sW[2] + sW[3];
    }

    // ---- pass 2: partial context from cache-hot enc chunk (fp32) ----
    int e0 = tid * 2;
    const float* ebase = enc + (size_t)m0 * H_ENC + e0;
    float cx = 0.0f, cy = 0.0f;
#pragma unroll 8
    for (int tt = 0; tt < BM; ++tt) {
        float wt = sP[tt];
        float2 x = *(const float2*)(ebase + (size_t)tt * H_ENC);
        cx += wt * x.x;
        cy += wt * x.y;
    }
    float* cp = ctxp + (size_t)chunk * H_ENC + e0;
    cp[0] = cx;
    cp[1] = cy;
}

// ---------------------------------------------------------------------------
// Kernel 3: combine — global softmax over 32 chunks, write attn + context
// ---------------------------------------------------------------------------
__global__ __launch_bounds__(256) void combine_kernel(
    const float* __restrict__ scores,  // (B*T)
    const float* __restrict__ ctxp,    // (NCHUNKS, 512)
    const float* __restrict__ ml,      // (NCHUNKS, 2)
    float* __restrict__ out)           // ctx (B,512) then attn (B,4096)
{
    __shared__ float sc[NCH_PER_B];
    __shared__ float sML[2];
    const int b = blockIdx.x;
    const int tid = threadIdx.x;
    const int nch = NCH_PER_B;  // 32

    float m_in = -INFINITY, l_in = 0.0f;
    if (tid < nch) {
        m_in = ml[(b * nch + tid) * 2];
        l_in = ml[(b * nch + tid) * 2 + 1];
    }
    if (tid < 64) {
        float M = m_in;
#pragma unroll
        for (int o = 1; o < 32; o <<= 1) M = fmaxf(M, __shfl_xor(M, o));
        float scale = (tid < nch) ? __expf(m_in - M) : 0.0f;
        float L = l_in * scale;
#pragma unroll
        for (int o = 1; o < 32; o <<= 1) L += __shfl_xor(L, o);
        if (tid < nch) sc[tid] = scale;
        if (tid == 0) { sML[0] = M; sML[1] = L; }
    }
    __syncthreads();
    const float M = sML[0];
    const float invL = 1.0f / sML[1];

    // attn weights: exact softmax from raw scores
    const float* sb = scores + (size_t)b * T_ENC;
    float* attn = out + B * H_ENC + (size_t)b * T_ENC;
#pragma unroll
    for (int i = 0; i < 16; ++i) {
        int t = i * 256 + tid;
        attn[t] = __expf(sb[t] - M) * invL;
    }

    // context: merge chunk partials
    int e0 = tid * 2;
    const float* cp = ctxp + ((size_t)b * nch) * H_ENC + e0;
    float cx = 0.0f, cy = 0.0f;
#pragma unroll 4
    for (int i = 0; i < nch; ++i) {
        float s2 = sc[i];
        float2 x = *(const float2*)(cp + (size_t)i * H_ENC);
        cx += s2 * x.x;
        cy += s2 * x.y;
    }
    out[b * H_ENC + e0]     = cx * invL;
    out[b * H_ENC + e0 + 1] = cy * invL;
}

extern "C" void kernel_launch(void* const* d_in, const int* in_sizes, int n_in,
                              void* d_out, int out_size, void* d_ws, size_t ws_size,
                              hipStream_t stream) {
    const float* dec  = (const float*)d_in[0];
    const float* enc  = (const float*)d_in[1];
    const float* Wenc = (const float*)d_in[2];
    const float* Wdec = (const float*)d_in[3];
    const float* v    = (const float*)d_in[4];
    float* out = (float*)d_out;
    float* ws  = (float*)d_ws;

    float* scores = ws;                                   // 262144 floats
    float* dproj  = scores + (size_t)B * T_ENC;           // 16384 floats
    unsigned short* wencb = (unsigned short*)(dproj + B * ATTN);  // 131072 shorts
    float* ctxp = dproj + B * ATTN + (ATTN * H_ENC) / 2;  // NCHUNKS*512 floats
    float* ml   = ctxp + (size_t)NCHUNKS * H_ENC;         // NCHUNKS*2 floats

    hipLaunchKernelGGL(convw_kernel, dim3((ATTN * H_ENC) / (256 * 8)), dim3(256), 0, stream,
                       Wenc, wencb);
    hipLaunchKernelGGL(decproj_kernel, dim3(B), dim3(256), 0, stream, dec, Wdec, dproj);
    hipLaunchKernelGGL(fused_kernel, dim3(NCHUNKS), dim3(256), 0, stream,
                       enc, wencb, dproj, v, scores, ctxp, ml);
    hipLaunchKernelGGL(combine_kernel, dim3(B), dim3(256), 0, stream,
                       scores, ctxp, ml, out);
}